// Round 13
// baseline (191.884 us; speedup 1.0000x reference)
//
#include <hip/hip_runtime.h>
#include <stdint.h>

typedef __attribute__((ext_vector_type(8))) short short8;
typedef __attribute__((ext_vector_type(4))) float floatx4;
typedef __attribute__((ext_vector_type(16))) float f32x16;
typedef __attribute__((ext_vector_type(4))) unsigned int uint4v;

#define D_MODEL 1024
#define SEQ     2048
#define NHEAD   16
#define HDIM    64
#define BATCH   4
#define NW      (D_MODEL * D_MODEL)

__device__ __forceinline__ unsigned short f2b(float f) {
  unsigned int u = __builtin_bit_cast(unsigned int, f);
  u += 0x7FFFu + ((u >> 16) & 1u);
  return (unsigned short)(u >> 16);
}

__device__ __forceinline__ floatx4 mfma16(short8 a, short8 b, floatx4 c) {
  return __builtin_amdgcn_mfma_f32_16x16x32_bf16(a, b, c, 0, 0, 0);
}
__device__ __forceinline__ f32x16 mfma32(short8 a, short8 b, f32x16 c) {
  return __builtin_amdgcn_mfma_f32_32x32x16_bf16(a, b, c, 0, 0, 0);
}
__device__ __forceinline__ unsigned int cvtpk(float lo, float hi) {
  unsigned int r;
  asm("v_cvt_pk_bf16_f32 %0, %1, %2" : "=v"(r) : "v"(lo), "v"(hi));
  return r;
}
__device__ __forceinline__ void pl32swap(unsigned int &a, unsigned int &b) {
  asm("v_permlane32_swap_b32 %0, %1" : "+v"(a), "+v"(b));
}
__device__ __forceinline__ float expfast(float x) {
  return __builtin_amdgcn_exp2f(x);
}

#define GLL16(gsrc, ldst)                                                     \
  __builtin_amdgcn_global_load_lds(                                           \
      (const __attribute__((address_space(1))) void*)(gsrc),                  \
      (__attribute__((address_space(3))) void*)(ldst), 16, 0, 0)

// ---------------- f32 -> bf16 conversion ----------------
__global__ void cvt_f32_bf16(const float* __restrict__ in,
                             unsigned short* __restrict__ out, int n) {
  int idx = (blockIdx.x * blockDim.x + threadIdx.x) * 4;
  int stride = gridDim.x * blockDim.x * 4;
  for (int i = idx; i < n; i += stride) {
    float4 v = *reinterpret_cast<const float4*>(in + i);
    ushort4 o;
    o.x = f2b(v.x); o.y = f2b(v.y); o.z = f2b(v.z); o.w = f2b(v.w);
    *reinterpret_cast<ushort4*>(out + i) = o;
  }
}

// Weights + mask prep
__global__ void cvt_w(const float* __restrict__ Wq, const float* __restrict__ Wk,
                      const float* __restrict__ Wv, const float* __restrict__ Wo,
                      unsigned short* __restrict__ Wqkv,
                      unsigned short* __restrict__ Wob,
                      const int* __restrict__ mask, float* __restrict__ maskb) {
  const int which = blockIdx.y;
  int idx = (blockIdx.x * blockDim.x + threadIdx.x) * 4;
  int stride = gridDim.x * blockDim.x * 4;
  if (which == 4) {
    for (int i = idx; i < BATCH * SEQ; i += stride) {
      int4 mv = *reinterpret_cast<const int4*>(mask + i);
      float4 o;
      o.x = mv.x ? 0.f : -1e10f;
      o.y = mv.y ? 0.f : -1e10f;
      o.z = mv.z ? 0.f : -1e10f;
      o.w = mv.w ? 0.f : -1e10f;
      *reinterpret_cast<float4*>(maskb + i) = o;
    }
    return;
  }
  const float* s = which == 0 ? Wq : which == 1 ? Wk : which == 2 ? Wv : Wo;
  unsigned short* d = which < 3 ? Wqkv + (size_t)which * NW : Wob;
  for (int i = idx; i < NW; i += stride) {
    float4 v = *reinterpret_cast<const float4*>(s + i);
    ushort4 o;
    o.x = f2b(v.x); o.y = f2b(v.y); o.z = f2b(v.z); o.w = f2b(v.w);
    *reinterpret_cast<ushort4*>(d + i) = o;
  }
}

// Per-(b, 64-key-chunk) "all keys valid" bitmask + bias concat (fused).
__global__ void mask_flags(const int* __restrict__ mask,
                           unsigned int* __restrict__ flags2,
                           const float* __restrict__ bq,
                           const float* __restrict__ bk,
                           const float* __restrict__ bv,
                           float* __restrict__ bqkv) {
  const int b = blockIdx.x, tid = threadIdx.x;
  if (tid < 64) {
    int ok = 0;
    if (tid < 32) {
      ok = 1;
      for (int i = 0; i < 64; ++i) ok &= mask[b * SEQ + tid * 64 + i];
    }
    unsigned long long bal = __ballot(ok);
    if (tid == 0) flags2[b] = (unsigned int)bal;
  }
  const int i = blockIdx.x * 256 + tid;  // 0..1023
  bqkv[i] = bq[i];
  bqkv[1024 + i] = bk[i];
  bqkv[2048 + i] = bv[i];
}

// ---------------- GEMM v3: 256x128 tile, 3-deep K-tile ring, 4-phase ----------
// 8 waves (4M x 2N), each 64x64 output. LDS: 3 K-tile buffers (A 32KB + B 16KB
// each). Stage K-tile t+2 during t's 4 phases; ONE vmcnt(6)+s_barrier per
// K-tile boundary (counted, never 0 until tail — T4). Per phase: ds_read
// subtile + stage portion + barrier + lgkmcnt(0) + 8 MFMA (T3 interleave).
// T2 swizzle (pre-swizzled global source col, XOR'd read). T1 XCD swizzle.
// MODE 1: QKV fused (Q pre-scale, V transposed to VT). MODE 2: f32 C.
template <int MODE>
__global__ __launch_bounds__(512) void gemm8(
    const unsigned short* __restrict__ A, const unsigned short* __restrict__ B,
    const float* __restrict__ bias, void* __restrict__ C,
    unsigned short* __restrict__ VT, int M, int N, int K) {
  __shared__ __align__(16) unsigned short As[3][256 * 64];  // 3 x 32KB
  __shared__ __align__(16) unsigned short Bs[3][128 * 64];  // 3 x 16KB
  const int tid = threadIdx.x;
  const int w = tid >> 6, l = tid & 63, lg = l >> 4, li = l & 15;
  const int GX = (MODE == 1) ? 24 : 8;   // N/128
  const int NWG = GX * (M >> 8);         // M/256 rows
  int id = blockIdx.y * GX + blockIdx.x;
  id = (id & 7) * (NWG >> 3) + (id >> 3);
  const int m0 = (id / GX) * 256, n0 = (id % GX) * 128;
  const int wr = w >> 1, wc = w & 1;  // wave 64x64 at (wr*64, wc*64)

  floatx4 acc[4][4];
#pragma unroll
  for (int m = 0; m < 4; ++m)
#pragma unroll
    for (int n = 0; n < 4; ++n) acc[m][n] = (floatx4){0.f, 0.f, 0.f, 0.f};

  // stage round P of A (P=0..3) / B (P=0..1) for K-tile T into buffer BUF.
  // chunk c = P*512+tid -> row=c>>3, slot=c&7; source col pre-swizzled.
#define STA(BUF, T, P)                                                         \
  do {                                                                         \
    const int c_ = (P) * 512 + tid;                                            \
    const int row_ = c_ >> 3;                                                  \
    const int co_ = ((c_ & 7) ^ (row_ & 7)) * 8;                               \
    GLL16(A + (size_t)(m0 + row_) * K + (T) * 64 + co_,                        \
          &As[BUF][((P) * 512 + w * 64) * 8]);                                 \
  } while (0)
#define STB(BUF, T, P)                                                         \
  do {                                                                         \
    const int c_ = (P) * 512 + tid;                                            \
    const int row_ = c_ >> 3;                                                  \
    const int co_ = ((c_ & 7) ^ (row_ & 7)) * 8;                               \
    GLL16(B + (size_t)(n0 + row_) * K + (T) * 64 + co_,                        \
          &Bs[BUF][((P) * 512 + w * 64) * 8]);                                 \
  } while (0)
#define STAGE6(BUF, T)                                                         \
  do {                                                                         \
    STA(BUF, T, 0); STA(BUF, T, 1); STA(BUF, T, 2); STA(BUF, T, 3);            \
    STB(BUF, T, 0); STB(BUF, T, 1);                                            \
  } while (0)

  // fragment reads (row&7 == li&7 since row = mult16 + li)
#define RA(BUF, MM, KK)                                                        \
  (*reinterpret_cast<const short8*>(                                           \
      &As[BUF][(wr * 64 + (MM) * 16 + li) * 64 + (((KK)*4 + lg) ^ (li & 7)) * 8]))
#define RB(BUF, NN, KK)                                                        \
  (*reinterpret_cast<const short8*>(                                           \
      &Bs[BUF][(wc * 64 + (NN) * 16 + li) * 64 + (((KK)*4 + lg) ^ (li & 7)) * 8]))

#define PHASE_SYNC()                                                           \
  do {                                                                         \
    __builtin_amdgcn_s_barrier();                                              \
    asm volatile("s_waitcnt lgkmcnt(0)" ::: "memory");                         \
    __builtin_amdgcn_sched_barrier(0);                                         \
  } while (0)

#define MFMA8(AF0, AF1, M0, M1)                                                \
  do {                                                                         \
    __builtin_amdgcn_s_setprio(1);                                             \
    acc[M0][0] = mfma16(AF0, bf0, acc[M0][0]);                                 \
    acc[M0][1] = mfma16(AF0, bf1, acc[M0][1]);                                 \
    acc[M0][2] = mfma16(AF0, bf2, acc[M0][2]);                                 \
    acc[M0][3] = mfma16(AF0, bf3, acc[M0][3]);                                 \
    acc[M1][0] = mfma16(AF1, bf0, acc[M1][0]);                                 \
    acc[M1][1] = mfma16(AF1, bf1, acc[M1][1]);                                 \
    acc[M1][2] = mfma16(AF1, bf2, acc[M1][2]);                                 \
    acc[M1][3] = mfma16(AF1, bf3, acc[M1][3]);                                 \
    __builtin_amdgcn_s_setprio(0);                                             \
  } while (0)

  // One K-tile: boundary vmcnt(VMC)+barrier, then 4 phases. Stages T+2 -> SB
  // when DOST (wave-uniform). vmcnt BEFORE barrier => every wave retired its
  // own tile-T loads before any wave reads tile-T data (v10-validated pattern).
#define KTILE(BUF, SB, T, VMC, DOST)                                           \
  do {                                                                         \
    asm volatile("s_waitcnt vmcnt(" #VMC ")" ::: "memory");                    \
    __builtin_amdgcn_s_barrier();                                              \
    __builtin_amdgcn_sched_barrier(0);                                         \
    /* phase 0: m0,m1 x kk0 */                                                 \
    short8 af0 = RA(BUF, 0, 0), af1 = RA(BUF, 1, 0);                           \
    short8 bf0 = RB(BUF, 0, 0), bf1 = RB(BUF, 1, 0);                           \
    short8 bf2 = RB(BUF, 2, 0), bf3 = RB(BUF, 3, 0);                           \
    if (DOST) { STA(SB, (T) + 2, 0); STA(SB, (T) + 2, 1); }                    \
    PHASE_SYNC();                                                              \
    MFMA8(af0, af1, 0, 1);                                                     \
    /* phase 1: m2,m3 x kk0 */                                                 \
    short8 af2 = RA(BUF, 2, 0), af3 = RA(BUF, 3, 0);                           \
    if (DOST) { STA(SB, (T) + 2, 2); STA(SB, (T) + 2, 3); }                    \
    PHASE_SYNC();                                                              \
    MFMA8(af2, af3, 2, 3);                                                     \
    /* phase 2: m0,m1 x kk1 */                                                 \
    af0 = RA(BUF, 0, 1); af1 = RA(BUF, 1, 1);                                  \
    bf0 = RB(BUF, 0, 1); bf1 = RB(BUF, 1, 1);                                  \
    bf2 = RB(BUF, 2, 1); bf3 = RB(BUF, 3, 1);                                  \
    if (DOST) { STB(SB, (T) + 2, 0); }                                         \
    PHASE_SYNC();                                                              \
    MFMA8(af0, af1, 0, 1);                                                     \
    /* phase 3: m2,m3 x kk1 */                                                 \
    af2 = RA(BUF, 2, 1); af3 = RA(BUF, 3, 1);                                  \
    if (DOST) { STB(SB, (T) + 2, 1); }                                         \
    PHASE_SYNC();                                                              \
    MFMA8(af2, af3, 2, 3);                                                     \
  } while (0)

  // K=1024 -> NT=16 K-tiles. Ring: buf = kt%3.
  STAGE6(0, 0);
  STAGE6(1, 1);
#pragma unroll 1
  for (int t = 0; t < 15; t += 3) {
    KTILE(0, 2, t, 6, true);               // stages t+2 (2,5,8,11,14)
    KTILE(1, 0, t + 1, 6, true);           // stages t+3 (3,6,9,12,15)
    KTILE(2, 1, t + 2, 6, (t + 4) < 16);   // stages t+4 (skip at t=12)
  }
  KTILE(0, 0, 15, 0, false);               // tail: drain
#undef STA
#undef STB
#undef STAGE6
#undef RA
#undef RB
#undef PHASE_SYNC
#undef MFMA8
#undef KTILE

#pragma unroll
  for (int m = 0; m < 4; ++m)
#pragma unroll
    for (int n = 0; n < 4; ++n) {
      const int gcol = n0 + wc * 64 + n * 16 + li;
      const float bv = bias[gcol];
      const int grow0 = m0 + wr * 64 + m * 16 + lg * 4;
      if (MODE == 1 && n0 >= 2048) {
        const int vc = gcol - 2048;
        const int hh = vc >> 6, dd = vc & 63;
        const int b = grow0 >> 11, s0 = grow0 & 2047;
        ushort4 pk;
        pk.x = f2b(acc[m][n][0] + bv);
        pk.y = f2b(acc[m][n][1] + bv);
        pk.z = f2b(acc[m][n][2] + bv);
        pk.w = f2b(acc[m][n][3] + bv);
        *reinterpret_cast<ushort4*>(
            &VT[((size_t)((b * NHEAD + hh) * HDIM + dd)) * SEQ + s0]) = pk;
      } else {
        const float scl =
            (MODE == 1 && gcol < 1024) ? 0.18033688011112042f : 1.f;
#pragma unroll
        for (int r = 0; r < 4; ++r) {
          const float val = (acc[m][n][r] + bv) * scl;
          if (MODE == 2)
            reinterpret_cast<float*>(C)[(size_t)(grow0 + r) * N + gcol] = val;
          else
            reinterpret_cast<unsigned short*>(C)[(size_t)(grow0 + r) * N + gcol] =
                f2b(val);
        }
      }
    }
}

// ---------------- Flash attention v7 (best: 95.6 us; frozen) ----------------
__global__ __launch_bounds__(512) void attn_v7(
    const unsigned short* __restrict__ QKV, const unsigned short* __restrict__ VT,
    const float* __restrict__ maskb, const unsigned int* __restrict__ flags2,
    unsigned short* __restrict__ O) {
  __shared__ __align__(16) unsigned short Kl[2][64 * 64];
  __shared__ __align__(16) unsigned short Vl[2][64 * 64];
  const int tid = threadIdx.x, w = tid >> 6, l = tid & 63;
  const int qi = l & 31, hi = l >> 5;
  const int bid = blockIdx.x;
  const int qblk = bid >> 6, bh = bid & 63, b = bh >> 4, h = bh & 15;
  const int q0 = qblk * 256 + w * 32;

  const unsigned short* qptr = QKV + (size_t)(b * SEQ + q0 + qi) * 3072 + h * 64;
  short8 qf[4];
#pragma unroll
  for (int ds = 0; ds < 4; ++ds)
    qf[ds] = *reinterpret_cast<const short8*>(qptr + ds * 16 + hi * 8);

  int off[2][4];
#pragma unroll
  for (int kb = 0; kb < 2; ++kb)
#pragma unroll
    for (int ds = 0; ds < 4; ++ds)
      off[kb][ds] = (kb * 32 + qi) * 64 + (((ds * 2 + hi) ^ (qi & 7)) * 8);

  const int srow = tid >> 3;
  const int swz = ((tid & 7) ^ (srow & 7)) * 8;
  const int ldst = w * 512;  // wave-uniform LDS base (ushort units)
  const unsigned short* kp0 =
      QKV + (size_t)(b * SEQ) * 3072 + D_MODEL + h * 64 + (size_t)srow * 3072 + swz;
  const unsigned short* vp0 =
      VT + (size_t)((b * NHEAD + h) * HDIM) * SEQ + (size_t)srow * SEQ + swz;

#define STAGE(BUF)                                                             \
  do {                                                                         \
    GLL16(kp0, &Kl[BUF][ldst]);                                                \
    GLL16(vp0, &Vl[BUF][ldst]);                                                \
    kp0 += 64 * 3072; vp0 += 64;                                               \
  } while (0)

  const float* mrow = maskb + b * SEQ;
  const unsigned int fl = flags2[b];
  f32x16 oa[2] = {};
  float l_run = 0.f;  // per-lane partial (own k-half); combined in epilogue

#define TILE(BUF, KT)                                                          \
  do {                                                                         \
    f32x16 pa0 = {}, pa1 = {};                                                 \
    __builtin_amdgcn_s_setprio(1);                                             \
    _Pragma("unroll") for (int ds = 0; ds < 4; ++ds) {                         \
      const short8 kf0 =                                                       \
          *reinterpret_cast<const short8*>(&Kl[BUF][off[0][ds]]);              \
      const short8 kf1 =                                                       \
          *reinterpret_cast<const short8*>(&Kl[BUF][off[1][ds]]);              \
      pa0 = mfma32(kf0, qf[ds], pa0);                                          \
      pa1 = mfma32(kf1, qf[ds], pa1);                                          \
    }                                                                          \
    __builtin_amdgcn_s_setprio(0);                                             \
    if (!((fl >> (KT)) & 1)) { /* slow path: some keys masked */               \
      _Pragma("unroll") for (int rq = 0; rq < 4; ++rq) {                       \
        const float4 m0 = *reinterpret_cast<const float4*>(                    \
            mrow + (KT) * 64 + rq * 8 + hi * 4);                               \
        const float4 m1 = *reinterpret_cast<const float4*>(                    \
            mrow + (KT) * 64 + 32 + rq * 8 + hi * 4);                          \
        pa0[rq * 4 + 0] += m0.x; pa0[rq * 4 + 1] += m0.y;                      \
        pa0[rq * 4 + 2] += m0.z; pa0[rq * 4 + 3] += m0.w;                      \
        pa1[rq * 4 + 0] += m1.x; pa1[rq * 4 + 1] += m1.y;                      \
        pa1[rq * 4 + 2] += m1.z; pa1[rq * 4 + 3] += m1.w;                      \
      }                                                                        \
    }                                                                          \
    float r0 = 0.f, r1 = 0.f, r2 = 0.f, r3 = 0.f;                              \
    _Pragma("unroll") for (int r = 0; r < 16; r += 4) {                        \
      float p;                                                                 \
      p = expfast(pa0[r + 0]); pa0[r + 0] = p; r0 += p;                        \
      p = expfast(pa0[r + 1]); pa0[r + 1] = p; r1 += p;                        \
      p = expfast(pa0[r + 2]); pa0[r + 2] = p; r2 += p;                        \
      p = expfast(pa0[r + 3]); pa0[r + 3] = p; r3 += p;                        \
      p = expfast(pa1[r + 0]); pa1[r + 0] = p; r0 += p;                        \
      p = expfast(pa1[r + 1]); pa1[r + 1] = p; r1 += p;                        \
      p = expfast(pa1[r + 2]); pa1[r + 2] = p; r2 += p;                        \
      p = expfast(pa1[r + 3]); pa1[r + 3] = p; r3 += p;                        \
    }                                                                          \
    l_run += (r0 + r1) + (r2 + r3);                                            \
    unsigned int c0[8], c1[8];                                                 \
    _Pragma("unroll") for (int u2 = 0; u2 < 8; ++u2) {                         \
      c0[u2] = cvtpk(pa0[2 * u2], pa0[2 * u2 + 1]);                            \
      c1[u2] = cvtpk(pa1[2 * u2], pa1[2 * u2 + 1]);                            \
    }                                                                          \
    pl32swap(c0[0], c0[2]); pl32swap(c0[1], c0[3]);                            \
    pl32swap(c0[4], c0[6]); pl32swap(c0[5], c0[7]);                            \
    pl32swap(c1[0], c1[2]); pl32swap(c1[1], c1[3]);                            \
    pl32swap(c1[4], c1[6]); pl32swap(c1[5], c1[7]);                            \
    __builtin_amdgcn_s_setprio(1);                                             \
    _Pragma("unroll") for (int ks = 0; ks < 4; ++ks) {                         \
      const int kb = ks >> 1, hf = (ks & 1) * 4;                               \
      const short8 pf = __builtin_bit_cast(                                    \
          short8, kb ? (uint4v){c1[hf], c1[hf + 1], c1[hf + 2], c1[hf + 3]}    \
                     : (uint4v){c0[hf], c0[hf + 1], c0[hf + 2], c0[hf + 3]});  \
      const short8 vf0 =                                                       \
          *reinterpret_cast<const short8*>(&Vl[BUF][off[0][ks]]);              \
      const short8 vf1 =                                                       \
          *reinterpret_cast<const short8*>(&Vl[BUF][off[1][ks]]);              \
      oa[0] = mfma32(vf0, pf, oa[0]);                                          \
      oa[1] = mfma32(vf1, pf, oa[1]);                                          \
    }                                                                          \
    __builtin_amdgcn_s_setprio(0);                                             \
  } while (0)

  STAGE(0);  // tile 0
  __syncthreads();
#pragma unroll 1
  for (int kt = 0; kt < 32; kt += 2) {
    STAGE(1);  // tile kt+1 in flight while computing kt
    TILE(0, kt);
    __syncthreads();
    if (kt + 2 < 32) STAGE(0);  // tile kt+2
    TILE(1, kt + 1);
    __syncthreads();
  }
#undef STAGE
#undef TILE

  // epilogue: combine lane-partial l across k-halves, normalize, repack, store
  l_run += __shfl_xor(l_run, 32);
  const float rinv = 1.f / l_run;
  unsigned int u[2][8];
#pragma unroll
  for (int vb = 0; vb < 2; ++vb) {
#pragma unroll
    for (int uu = 0; uu < 8; ++uu)
      u[vb][uu] = cvtpk(oa[vb][2 * uu] * rinv, oa[vb][2 * uu + 1] * rinv);
    pl32swap(u[vb][0], u[vb][2]);
    pl32swap(u[vb][1], u[vb][3]);
    pl32swap(u[vb][4], u[vb][6]);
    pl32swap(u[vb][5], u[vb][7]);
  }
  unsigned short* optr = O + (size_t)(b * SEQ + q0 + qi) * D_MODEL + h * 64;
#pragma unroll
  for (int cix = 0; cix < 4; ++cix) {
    const int vb = cix >> 1, hf = (cix & 1) * 4;
    *reinterpret_cast<short8*>(optr + cix * 16 + hi * 8) = __builtin_bit_cast(
        short8,
        (uint4v){u[vb][hf], u[vb][hf + 1], u[vb][hf + 2], u[vb][hf + 3]});
  }
}

// ---------------- launch ----------------
extern "C" void kernel_launch(void* const* d_in, const int* in_sizes, int n_in,
                              void* d_out, int out_size, void* d_ws, size_t ws_size,
                              hipStream_t stream) {
  const float* x  = (const float*)d_in[0];
  const int* mask = (const int*)d_in[1];
  const float* Wq = (const float*)d_in[2];
  const float* bq = (const float*)d_in[3];
  const float* Wk = (const float*)d_in[4];
  const float* bk = (const float*)d_in[5];
  const float* Wv = (const float*)d_in[6];
  const float* bv = (const float*)d_in[7];
  const float* Wo = (const float*)d_in[8];
  const float* bo = (const float*)d_in[9];

  char* ws = (char*)d_ws;
  const size_t SZ_X = (size_t)BATCH * SEQ * D_MODEL * 2;  // 16 MB
  unsigned short* xb    = (unsigned short*)(ws);                    // 16 MB @ 0
  unsigned short* Wqkvb = (unsigned short*)(ws + SZ_X);             // 6 MB @ 16M
  unsigned short* Wob   = (unsigned short*)(ws + SZ_X + 6u * 1024 * 1024);  // @ 22M
  unsigned short* QKVb  = (unsigned short*)(ws + 24u * 1024 * 1024);        // 48 MB
  unsigned short* VTb   = (unsigned short*)(ws + 72u * 1024 * 1024);        // 16 MB
  float*          bqkv  = (float*)(ws + 88u * 1024 * 1024);                 // 12 KB
  float*          maskb = (float*)(ws + 88u * 1024 * 1024 + 16384);         // 32 KB
  unsigned int*   flag2 = (unsigned int*)(ws + 88u * 1024 * 1024 + 49152);  // 16 B
  unsigned short* Ob    = xb;  // reuse: xb dead after QKV GEMM

  const int NX = BATCH * SEQ * D_MODEL;  // 8388608
  const int M = BATCH * SEQ;             // 8192

  cvt_f32_bf16<<<2048, 256, 0, stream>>>(x, xb, NX);
  cvt_w<<<dim3(512, 5), 256, 0, stream>>>(Wq, Wk, Wv, Wo, Wqkvb, Wob, mask, maskb);
  mask_flags<<<BATCH, 256, 0, stream>>>(mask, flag2, bq, bk, bv, bqkv);

  gemm8<1><<<dim3(3 * D_MODEL / 128, M / 256), 512, 0, stream>>>(
      xb, Wqkvb, bqkv, QKVb, VTb, M, 3 * D_MODEL, D_MODEL);

  attn_v7<<<BATCH * NHEAD * (SEQ / 256), 512, 0, stream>>>(QKVb, VTb, maskb,
                                                           flag2, Ob);

  gemm8<2><<<dim3(D_MODEL / 128, M / 256), 512, 0, stream>>>(
      Ob, Wob, bo, d_out, nullptr, M, D_MODEL, D_MODEL);
}

// Round 14
// 182.065 us; speedup vs baseline: 1.0539x; 1.0539x over previous
//
#include <hip/hip_runtime.h>
#include <stdint.h>

typedef __attribute__((ext_vector_type(8))) short short8;
typedef __attribute__((ext_vector_type(4))) float floatx4;
typedef __attribute__((ext_vector_type(16))) float f32x16;
typedef __attribute__((ext_vector_type(4))) unsigned int uint4v;

#define D_MODEL 1024
#define SEQ     2048
#define NHEAD   16
#define HDIM    64
#define BATCH   4
#define NW      (D_MODEL * D_MODEL)

__device__ __forceinline__ unsigned short f2b(float f) {
  unsigned int u = __builtin_bit_cast(unsigned int, f);
  u += 0x7FFFu + ((u >> 16) & 1u);
  return (unsigned short)(u >> 16);
}

__device__ __forceinline__ floatx4 mfma16(short8 a, short8 b, floatx4 c) {
  return __builtin_amdgcn_mfma_f32_16x16x32_bf16(a, b, c, 0, 0, 0);
}
__device__ __forceinline__ f32x16 mfma32(short8 a, short8 b, f32x16 c) {
  return __builtin_amdgcn_mfma_f32_32x32x16_bf16(a, b, c, 0, 0, 0);
}
__device__ __forceinline__ unsigned int cvtpk(float lo, float hi) {
  unsigned int r;
  asm("v_cvt_pk_bf16_f32 %0, %1, %2" : "=v"(r) : "v"(lo), "v"(hi));
  return r;
}
__device__ __forceinline__ void pl32swap(unsigned int &a, unsigned int &b) {
  asm("v_permlane32_swap_b32 %0, %1" : "+v"(a), "+v"(b));
}
__device__ __forceinline__ float expfast(float x) {
  return __builtin_amdgcn_exp2f(x);
}

#define GLL16(gsrc, ldst)                                                     \
  __builtin_amdgcn_global_load_lds(                                           \
      (const __attribute__((address_space(1))) void*)(gsrc),                  \
      (__attribute__((address_space(3))) void*)(ldst), 16, 0, 0)

// ---------------- fused prep: weights cvt + mask prep + x cvt ----------------
// blockIdx.y: 0..3 -> Wq,Wk,Wv (into Wqkv) / Wo cvt; 4 -> mask bias + per-64-
// chunk valid flags + bias concat; 5 -> x cvt. All branches independent; one
// launch runs them concurrently instead of 3 serialized launches.
__global__ void prep(const float* __restrict__ x, unsigned short* __restrict__ xb,
                     const float* __restrict__ Wq, const float* __restrict__ Wk,
                     const float* __restrict__ Wv, const float* __restrict__ Wo,
                     unsigned short* __restrict__ Wqkv,
                     unsigned short* __restrict__ Wob,
                     const int* __restrict__ mask, float* __restrict__ maskb,
                     unsigned int* __restrict__ flags2,
                     const float* __restrict__ bq, const float* __restrict__ bk,
                     const float* __restrict__ bv, float* __restrict__ bqkv) {
  const int which = blockIdx.y;
  const int tid = threadIdx.x;
  int idx = (blockIdx.x * 256 + tid) * 4;
  int stride = gridDim.x * 256 * 4;
  if (which == 4) {
    for (int i = idx; i < BATCH * SEQ; i += stride) {
      int4 mv = *reinterpret_cast<const int4*>(mask + i);
      float4 o;
      o.x = mv.x ? 0.f : -1e10f;
      o.y = mv.y ? 0.f : -1e10f;
      o.z = mv.z ? 0.f : -1e10f;
      o.w = mv.w ? 0.f : -1e10f;
      *reinterpret_cast<float4*>(maskb + i) = o;
    }
    if (blockIdx.x < 4) {
      const int b = blockIdx.x;
      if (tid < 64) {
        int ok = 0;
        if (tid < 32) {
          ok = 1;
          for (int i = 0; i < 64; ++i) ok &= mask[b * SEQ + tid * 64 + i];
        }
        unsigned long long bal = __ballot(ok);
        if (tid == 0) flags2[b] = (unsigned int)bal;
      }
      const int i = b * 256 + tid;  // 0..1023
      bqkv[i] = bq[i];
      bqkv[1024 + i] = bk[i];
      bqkv[2048 + i] = bv[i];
    }
    return;
  }
  if (which == 5) {
    const int NX = BATCH * SEQ * D_MODEL;
    for (int i = idx; i < NX; i += stride) {
      float4 v = *reinterpret_cast<const float4*>(x + i);
      ushort4 o;
      o.x = f2b(v.x); o.y = f2b(v.y); o.z = f2b(v.z); o.w = f2b(v.w);
      *reinterpret_cast<ushort4*>(xb + i) = o;
    }
    return;
  }
  const float* s = which == 0 ? Wq : which == 1 ? Wk : which == 2 ? Wv : Wo;
  unsigned short* d = which < 3 ? Wqkv + (size_t)which * NW : Wob;
  for (int i = idx; i < NW; i += stride) {
    float4 v = *reinterpret_cast<const float4*>(s + i);
    ushort4 o;
    o.x = f2b(v.x); o.y = f2b(v.y); o.z = f2b(v.z); o.w = f2b(v.w);
    *reinterpret_cast<ushort4*>(d + i) = o;
  }
}

// ---------------- GEMM v2: double-buffered 2-phase + T2 swizzle ----------------
// (R9 state — best measured; at the documented 2-phase structural ceiling.)
template <int MODE>
__global__ __launch_bounds__(256) void gemm_bt(
    const unsigned short* __restrict__ A, const unsigned short* __restrict__ B,
    const float* __restrict__ bias, void* __restrict__ C,
    unsigned short* __restrict__ VT, int M, int N, int K) {
  __shared__ __align__(16) unsigned short As[2][128 * 64];
  __shared__ __align__(16) unsigned short Bs[2][128 * 64];
  const int tid = threadIdx.x;
  const int w = tid >> 6, l = tid & 63, lg = l >> 4, li = l & 15;
  const int GX = (MODE == 1) ? 24 : 8;      // N/128
  const int NWG = GX * 64;                   // M/128 = 64
  int id = blockIdx.y * GX + blockIdx.x;
  id = (id & 7) * (NWG >> 3) + (id >> 3);
  const int m0 = (id / GX) * 128, n0 = (id % GX) * 128;
  const int wr = w >> 1, wc = w & 1;

  floatx4 acc[4][4];
#pragma unroll
  for (int m = 0; m < 4; ++m)
#pragma unroll
    for (int n = 0; n < 4; ++n) acc[m][n] = (floatx4){0.f, 0.f, 0.f, 0.f};

#define GSTAGE(BUF, T)                                                         \
  do {                                                                         \
    _Pragma("unroll") for (int p = 0; p < 4; ++p) {                            \
      const int c = p * 256 + tid;                                             \
      const int row = c >> 3;                                                  \
      const int co = ((c & 7) ^ (row & 7)) * 8;                                \
      GLL16(A + (size_t)(m0 + row) * K + (T) * 64 + co,                        \
            &As[BUF][(p * 256 + w * 64) * 8]);                                 \
      GLL16(B + (size_t)(n0 + row) * K + (T) * 64 + co,                        \
            &Bs[BUF][(p * 256 + w * 64) * 8]);                                 \
    }                                                                          \
  } while (0)

#define GCOMP(BUF)                                                             \
  do {                                                                         \
    _Pragma("unroll") for (int kk = 0; kk < 2; ++kk) {                         \
      short8 af[4], bfr[4];                                                    \
      _Pragma("unroll") for (int m = 0; m < 4; ++m)                            \
        af[m] = *reinterpret_cast<const short8*>(                              \
            &As[BUF][(wr * 64 + m * 16 + li) * 64 +                            \
                     (((kk * 4 + lg) ^ (li & 7)) * 8)]);                       \
      _Pragma("unroll") for (int n = 0; n < 4; ++n)                            \
        bfr[n] = *reinterpret_cast<const short8*>(                             \
            &Bs[BUF][(wc * 64 + n * 16 + li) * 64 +                            \
                     (((kk * 4 + lg) ^ (li & 7)) * 8)]);                       \
      __builtin_amdgcn_s_setprio(1);                                           \
      _Pragma("unroll") for (int m = 0; m < 4; ++m)                            \
        _Pragma("unroll") for (int n = 0; n < 4; ++n)                          \
            acc[m][n] = mfma16(af[m], bfr[n], acc[m][n]);                      \
      __builtin_amdgcn_s_setprio(0);                                           \
    }                                                                          \
  } while (0)

  const int NT = K >> 6;  // 16 for K=1024
  GSTAGE(0, 0);
  __syncthreads();
#pragma unroll 1
  for (int t = 0; t < NT; t += 2) {
    if (t + 1 < NT) GSTAGE(1, t + 1);
    GCOMP(0);
    __syncthreads();
    if (t + 2 < NT) GSTAGE(0, t + 2);
    GCOMP(1);
    __syncthreads();
  }
#undef GSTAGE
#undef GCOMP

#pragma unroll
  for (int m = 0; m < 4; ++m)
#pragma unroll
    for (int n = 0; n < 4; ++n) {
      const int gcol = n0 + wc * 64 + n * 16 + li;
      const float bv = bias[gcol];
      const int grow0 = m0 + wr * 64 + m * 16 + lg * 4;
      if (MODE == 1 && n0 >= 2048) {
        const int vc = gcol - 2048;
        const int hh = vc >> 6, dd = vc & 63;
        const int b = grow0 >> 11, s0 = grow0 & 2047;
        ushort4 pk;
        pk.x = f2b(acc[m][n][0] + bv);
        pk.y = f2b(acc[m][n][1] + bv);
        pk.z = f2b(acc[m][n][2] + bv);
        pk.w = f2b(acc[m][n][3] + bv);
        *reinterpret_cast<ushort4*>(
            &VT[((size_t)((b * NHEAD + hh) * HDIM + dd)) * SEQ + s0]) = pk;
      } else {
        const float scl =
            (MODE == 1 && gcol < 1024) ? 0.18033688011112042f : 1.f;
#pragma unroll
        for (int r = 0; r < 4; ++r) {
          const float val = (acc[m][n][r] + bv) * scl;
          if (MODE == 2)
            reinterpret_cast<float*>(C)[(size_t)(grow0 + r) * N + gcol] = val;
          else
            reinterpret_cast<unsigned short*>(C)[(size_t)(grow0 + r) * N + gcol] =
                f2b(val);
        }
      }
    }
}

// ---------------- Flash attention v7 (best: 95.6 us; frozen) ----------------
__global__ __launch_bounds__(512) void attn_v7(
    const unsigned short* __restrict__ QKV, const unsigned short* __restrict__ VT,
    const float* __restrict__ maskb, const unsigned int* __restrict__ flags2,
    unsigned short* __restrict__ O) {
  __shared__ __align__(16) unsigned short Kl[2][64 * 64];
  __shared__ __align__(16) unsigned short Vl[2][64 * 64];
  const int tid = threadIdx.x, w = tid >> 6, l = tid & 63;
  const int qi = l & 31, hi = l >> 5;
  const int bid = blockIdx.x;
  const int qblk = bid >> 6, bh = bid & 63, b = bh >> 4, h = bh & 15;
  const int q0 = qblk * 256 + w * 32;

  const unsigned short* qptr = QKV + (size_t)(b * SEQ + q0 + qi) * 3072 + h * 64;
  short8 qf[4];
#pragma unroll
  for (int ds = 0; ds < 4; ++ds)
    qf[ds] = *reinterpret_cast<const short8*>(qptr + ds * 16 + hi * 8);

  int off[2][4];
#pragma unroll
  for (int kb = 0; kb < 2; ++kb)
#pragma unroll
    for (int ds = 0; ds < 4; ++ds)
      off[kb][ds] = (kb * 32 + qi) * 64 + (((ds * 2 + hi) ^ (qi & 7)) * 8);

  const int srow = tid >> 3;
  const int swz = ((tid & 7) ^ (srow & 7)) * 8;
  const int ldst = w * 512;  // wave-uniform LDS base (ushort units)
  const unsigned short* kp0 =
      QKV + (size_t)(b * SEQ) * 3072 + D_MODEL + h * 64 + (size_t)srow * 3072 + swz;
  const unsigned short* vp0 =
      VT + (size_t)((b * NHEAD + h) * HDIM) * SEQ + (size_t)srow * SEQ + swz;

#define STAGE(BUF)                                                             \
  do {                                                                         \
    GLL16(kp0, &Kl[BUF][ldst]);                                                \
    GLL16(vp0, &Vl[BUF][ldst]);                                                \
    kp0 += 64 * 3072; vp0 += 64;                                               \
  } while (0)

  const float* mrow = maskb + b * SEQ;
  const unsigned int fl = flags2[b];
  f32x16 oa[2] = {};
  float l_run = 0.f;  // per-lane partial (own k-half); combined in epilogue

#define TILE(BUF, KT)                                                          \
  do {                                                                         \
    f32x16 pa0 = {}, pa1 = {};                                                 \
    __builtin_amdgcn_s_setprio(1);                                             \
    _Pragma("unroll") for (int ds = 0; ds < 4; ++ds) {                         \
      const short8 kf0 =                                                       \
          *reinterpret_cast<const short8*>(&Kl[BUF][off[0][ds]]);              \
      const short8 kf1 =                                                       \
          *reinterpret_cast<const short8*>(&Kl[BUF][off[1][ds]]);              \
      pa0 = mfma32(kf0, qf[ds], pa0);                                          \
      pa1 = mfma32(kf1, qf[ds], pa1);                                          \
    }                                                                          \
    __builtin_amdgcn_s_setprio(0);                                             \
    if (!((fl >> (KT)) & 1)) { /* slow path: some keys masked */               \
      _Pragma("unroll") for (int rq = 0; rq < 4; ++rq) {                       \
        const float4 m0 = *reinterpret_cast<const float4*>(                    \
            mrow + (KT) * 64 + rq * 8 + hi * 4);                               \
        const float4 m1 = *reinterpret_cast<const float4*>(                    \
            mrow + (KT) * 64 + 32 + rq * 8 + hi * 4);                          \
        pa0[rq * 4 + 0] += m0.x; pa0[rq * 4 + 1] += m0.y;                      \
        pa0[rq * 4 + 2] += m0.z; pa0[rq * 4 + 3] += m0.w;                      \
        pa1[rq * 4 + 0] += m1.x; pa1[rq * 4 + 1] += m1.y;                      \
        pa1[rq * 4 + 2] += m1.z; pa1[rq * 4 + 3] += m1.w;                      \
      }                                                                        \
    }                                                                          \
    float r0 = 0.f, r1 = 0.f, r2 = 0.f, r3 = 0.f;                              \
    _Pragma("unroll") for (int r = 0; r < 16; r += 4) {                        \
      float p;                                                                 \
      p = expfast(pa0[r + 0]); pa0[r + 0] = p; r0 += p;                        \
      p = expfast(pa0[r + 1]); pa0[r + 1] = p; r1 += p;                        \
      p = expfast(pa0[r + 2]); pa0[r + 2] = p; r2 += p;                        \
      p = expfast(pa0[r + 3]); pa0[r + 3] = p; r3 += p;                        \
      p = expfast(pa1[r + 0]); pa1[r + 0] = p; r0 += p;                        \
      p = expfast(pa1[r + 1]); pa1[r + 1] = p; r1 += p;                        \
      p = expfast(pa1[r + 2]); pa1[r + 2] = p; r2 += p;                        \
      p = expfast(pa1[r + 3]); pa1[r + 3] = p; r3 += p;                        \
    }                                                                          \
    l_run += (r0 + r1) + (r2 + r3);                                            \
    unsigned int c0[8], c1[8];                                                 \
    _Pragma("unroll") for (int u2 = 0; u2 < 8; ++u2) {                         \
      c0[u2] = cvtpk(pa0[2 * u2], pa0[2 * u2 + 1]);                            \
      c1[u2] = cvtpk(pa1[2 * u2], pa1[2 * u2 + 1]);                            \
    }                                                                          \
    pl32swap(c0[0], c0[2]); pl32swap(c0[1], c0[3]);                            \
    pl32swap(c0[4], c0[6]); pl32swap(c0[5], c0[7]);                            \
    pl32swap(c1[0], c1[2]); pl32swap(c1[1], c1[3]);                            \
    pl32swap(c1[4], c1[6]); pl32swap(c1[5], c1[7]);                            \
    __builtin_amdgcn_s_setprio(1);                                             \
    _Pragma("unroll") for (int ks = 0; ks < 4; ++ks) {                         \
      const int kb = ks >> 1, hf = (ks & 1) * 4;                               \
      const short8 pf = __builtin_bit_cast(                                    \
          short8, kb ? (uint4v){c1[hf], c1[hf + 1], c1[hf + 2], c1[hf + 3]}    \
                     : (uint4v){c0[hf], c0[hf + 1], c0[hf + 2], c0[hf + 3]});  \
      const short8 vf0 =                                                       \
          *reinterpret_cast<const short8*>(&Vl[BUF][off[0][ks]]);              \
      const short8 vf1 =                                                       \
          *reinterpret_cast<const short8*>(&Vl[BUF][off[1][ks]]);              \
      oa[0] = mfma32(vf0, pf, oa[0]);                                          \
      oa[1] = mfma32(vf1, pf, oa[1]);                                          \
    }                                                                          \
    __builtin_amdgcn_s_setprio(0);                                             \
  } while (0)

  STAGE(0);  // tile 0
  __syncthreads();
#pragma unroll 1
  for (int kt = 0; kt < 32; kt += 2) {
    STAGE(1);  // tile kt+1 in flight while computing kt
    TILE(0, kt);
    __syncthreads();
    if (kt + 2 < 32) STAGE(0);  // tile kt+2
    TILE(1, kt + 1);
    __syncthreads();
  }
#undef STAGE
#undef TILE

  // epilogue: combine lane-partial l across k-halves, normalize, repack, store
  l_run += __shfl_xor(l_run, 32);
  const float rinv = 1.f / l_run;
  unsigned int u[2][8];
#pragma unroll
  for (int vb = 0; vb < 2; ++vb) {
#pragma unroll
    for (int uu = 0; uu < 8; ++uu)
      u[vb][uu] = cvtpk(oa[vb][2 * uu] * rinv, oa[vb][2 * uu + 1] * rinv);
    pl32swap(u[vb][0], u[vb][2]);
    pl32swap(u[vb][1], u[vb][3]);
    pl32swap(u[vb][4], u[vb][6]);
    pl32swap(u[vb][5], u[vb][7]);
  }
  unsigned short* optr = O + (size_t)(b * SEQ + q0 + qi) * D_MODEL + h * 64;
#pragma unroll
  for (int cix = 0; cix < 4; ++cix) {
    const int vb = cix >> 1, hf = (cix & 1) * 4;
    *reinterpret_cast<short8*>(optr + cix * 16 + hi * 8) = __builtin_bit_cast(
        short8,
        (uint4v){u[vb][hf], u[vb][hf + 1], u[vb][hf + 2], u[vb][hf + 3]});
  }
}

// ---------------- launch ----------------
extern "C" void kernel_launch(void* const* d_in, const int* in_sizes, int n_in,
                              void* d_out, int out_size, void* d_ws, size_t ws_size,
                              hipStream_t stream) {
  const float* x  = (const float*)d_in[0];
  const int* mask = (const int*)d_in[1];
  const float* Wq = (const float*)d_in[2];
  const float* bq = (const float*)d_in[3];
  const float* Wk = (const float*)d_in[4];
  const float* bk = (const float*)d_in[5];
  const float* Wv = (const float*)d_in[6];
  const float* bv = (const float*)d_in[7];
  const float* Wo = (const float*)d_in[8];
  const float* bo = (const float*)d_in[9];

  char* ws = (char*)d_ws;
  const size_t SZ_X = (size_t)BATCH * SEQ * D_MODEL * 2;  // 16 MB
  unsigned short* xb    = (unsigned short*)(ws);                    // 16 MB @ 0
  unsigned short* Wqkvb = (unsigned short*)(ws + SZ_X);             // 6 MB @ 16M
  unsigned short* Wob   = (unsigned short*)(ws + SZ_X + 6u * 1024 * 1024);  // @ 22M
  unsigned short* QKVb  = (unsigned short*)(ws + 24u * 1024 * 1024);        // 48 MB
  unsigned short* VTb   = (unsigned short*)(ws + 72u * 1024 * 1024);        // 16 MB
  float*          bqkv  = (float*)(ws + 88u * 1024 * 1024);                 // 12 KB
  float*          maskb = (float*)(ws + 88u * 1024 * 1024 + 16384);         // 32 KB
  unsigned int*   flag2 = (unsigned int*)(ws + 88u * 1024 * 1024 + 49152);  // 16 B
  unsigned short* Ob    = xb;  // reuse: xb dead after QKV GEMM

  const int M = BATCH * SEQ;             // 8192

  prep<<<dim3(512, 6), 256, 0, stream>>>(x, xb, Wq, Wk, Wv, Wo, Wqkvb, Wob,
                                         mask, maskb, flag2, bq, bk, bv, bqkv);

  gemm_bt<1><<<dim3(3 * D_MODEL / 128, M / 128), 256, 0, stream>>>(
      xb, Wqkvb, bqkv, QKVb, VTb, M, 3 * D_MODEL, D_MODEL);

  attn_v7<<<BATCH * NHEAD * (SEQ / 256), 512, 0, stream>>>(QKVb, VTb, maskb,
                                                           flag2, Ob);

  gemm_bt<2><<<dim3(D_MODEL / 128, M / 128), 256, 0, stream>>>(
      Ob, Wob, bo, d_out, nullptr, M, D_MODEL, D_MODEL);
}